// Round 1
// baseline (627.664 us; speedup 1.0000x reference)
//
#include <hip/hip_runtime.h>

// ---------------------------------------------------------------------------
// GPT-2 block: LN1 -> QKV GEMM -> causal flash attn -> proj+res -> LN2 ->
//              FC+GELU -> proj+res
// B=4 T=2048 C=768 H=12 HD=64. All MFMA bf16 (16x16x32), fp32 accum.
// ---------------------------------------------------------------------------

typedef unsigned short u16;
typedef __attribute__((ext_vector_type(8))) short short8;  // 8 bf16 = 4 VGPR
typedef __attribute__((ext_vector_type(4))) float f32x4;   // MFMA C/D

__device__ __forceinline__ u16 f2bf(float f) {
    union { float f; unsigned u; } v; v.f = f;
    unsigned u = v.u;
    unsigned r = (u + 0x7FFFu + ((u >> 16) & 1u)) >> 16;
    return (u16)r;
}
__device__ __forceinline__ float bf2f(u16 h) {
    union { unsigned u; float f; } v; v.u = ((unsigned)h) << 16;
    return v.f;
}

// ---------------------------------------------------------------------------
// Weight transpose+convert: fp32 W[K][N] -> bf16 Wt[N][K]
// ---------------------------------------------------------------------------
__global__ void transpose_bf16_kernel(const float* __restrict__ w,
                                      u16* __restrict__ wt, int K, int N) {
    __shared__ float t[32][33];
    int n0 = blockIdx.x * 32, k0 = blockIdx.y * 32;
    int tx = threadIdx.x, ty = threadIdx.y;  // 32 x 8
#pragma unroll
    for (int i = 0; i < 4; i++)
        t[ty + 8 * i][tx] = w[(size_t)(k0 + ty + 8 * i) * N + n0 + tx];
    __syncthreads();
#pragma unroll
    for (int i = 0; i < 4; i++)
        wt[(size_t)(n0 + ty + 8 * i) * K + k0 + tx] = f2bf(t[tx][ty + 8 * i]);
}

// ---------------------------------------------------------------------------
// LayerNorm: fp32 [rows][768] -> bf16 [rows][768]
// ---------------------------------------------------------------------------
__global__ void ln_kernel(const float* __restrict__ x, const float* __restrict__ s,
                          const float* __restrict__ b, u16* __restrict__ out) {
    int row = blockIdx.x;
    int tid = threadIdx.x;
    const float* xr = x + (size_t)row * 768;
    float v0 = xr[tid], v1 = xr[tid + 256], v2 = xr[tid + 512];
    float sum = v0 + v1 + v2;
    float sq = v0 * v0 + v1 * v1 + v2 * v2;
#pragma unroll
    for (int off = 32; off; off >>= 1) {
        sum += __shfl_down(sum, off);
        sq += __shfl_down(sq, off);
    }
    __shared__ float red[8];
    int wid = tid >> 6, lane = tid & 63;
    if (lane == 0) { red[wid] = sum; red[4 + wid] = sq; }
    __syncthreads();
    if (tid == 0) {
        float s4 = red[0] + red[1] + red[2] + red[3];
        float q4 = red[4] + red[5] + red[6] + red[7];
        red[0] = s4 * (1.0f / 768.0f);
        red[1] = q4 * (1.0f / 768.0f);
    }
    __syncthreads();
    float mean = red[0];
    float var = red[1] - mean * mean;
    float rstd = rsqrtf(var + 1e-5f);
    u16* orow = out + (size_t)row * 768;
    orow[tid]       = f2bf((v0 - mean) * rstd * s[tid]       + b[tid]);
    orow[tid + 256] = f2bf((v1 - mean) * rstd * s[tid + 256] + b[tid + 256]);
    orow[tid + 512] = f2bf((v2 - mean) * rstd * s[tid + 512] + b[tid + 512]);
}

// ---------------------------------------------------------------------------
// GEMM: out = act(A[M,K]bf16 @ Wt[N,K]^T bf16 + bias [+ res]) ; out fp32/bf16
// BM=BN=128, BK=64, 256 threads = 4 waves (2x2), each wave 64x64 = 4x4 frags.
// ---------------------------------------------------------------------------
template <int GELU, int RES, int OUTBF>
__global__ __launch_bounds__(256) void gemm_kernel(
    const u16* __restrict__ A, const u16* __restrict__ Wt,
    const float* __restrict__ bias, const float* __restrict__ res,
    void* __restrict__ out, int M, int N, int K) {
    __shared__ __align__(16) u16 lA[128 * 72];  // pad 8 bf16 -> conflict-free
    __shared__ __align__(16) u16 lB[128 * 72];
    int m0 = blockIdx.x * 128, n0 = blockIdx.y * 128;
    int tid = threadIdx.x;
    int wid = tid >> 6, lane = tid & 63;
    int wr = wid >> 1, wc = wid & 1;
    int l15 = lane & 15, lhi = lane >> 4;

    f32x4 acc[4][4];
#pragma unroll
    for (int i = 0; i < 4; i++)
#pragma unroll
        for (int j = 0; j < 4; j++) acc[i][j] = (f32x4)0.0f;

    for (int k0 = 0; k0 < K; k0 += 64) {
        // stage A tile [128][64] and Wt tile [128][64]
#pragma unroll
        for (int i = tid; i < 1024; i += 256) {
            int row = i >> 3, c = i & 7;
            *(float4*)(&lA[row * 72 + c * 8]) =
                *(const float4*)(A + (size_t)(m0 + row) * K + k0 + c * 8);
        }
#pragma unroll
        for (int i = tid; i < 1024; i += 256) {
            int row = i >> 3, c = i & 7;
            *(float4*)(&lB[row * 72 + c * 8]) =
                *(const float4*)(Wt + (size_t)(n0 + row) * K + k0 + c * 8);
        }
        __syncthreads();
        short8 af[2][4], bfr[2][4];
#pragma unroll
        for (int ks = 0; ks < 2; ks++)
#pragma unroll
            for (int f = 0; f < 4; f++) {
                af[ks][f] = *(const short8*)(&lA[(wr * 64 + f * 16 + l15) * 72 + ks * 32 + lhi * 8]);
                bfr[ks][f] = *(const short8*)(&lB[(wc * 64 + f * 16 + l15) * 72 + ks * 32 + lhi * 8]);
            }
#pragma unroll
        for (int ks = 0; ks < 2; ks++)
#pragma unroll
            for (int fm = 0; fm < 4; fm++)
#pragma unroll
                for (int fn = 0; fn < 4; fn++)
                    acc[fm][fn] = __builtin_amdgcn_mfma_f32_16x16x32_bf16(
                        af[ks][fm], bfr[ks][fn], acc[fm][fn], 0, 0, 0);
        __syncthreads();
    }
    // epilogue: D layout row=(lane>>4)*4+r, col=lane&15
#pragma unroll
    for (int fm = 0; fm < 4; fm++)
#pragma unroll
        for (int fn = 0; fn < 4; fn++) {
            int col = n0 + wc * 64 + fn * 16 + l15;
            float bv = bias[col];
#pragma unroll
            for (int r = 0; r < 4; r++) {
                int row = m0 + wr * 64 + fm * 16 + lhi * 4 + r;
                float v = acc[fm][fn][r] + bv;
                if (RES) v += res[(size_t)row * N + col];
                if (GELU) {
                    float z = 0.7978845608028654f * (v + 0.044715f * v * v * v);
                    v = 0.5f * v * (1.0f + tanhf(z));
                }
                if (OUTBF)
                    ((u16*)out)[(size_t)row * N + col] = f2bf(v);
                else
                    ((float*)out)[(size_t)row * N + col] = v;
            }
        }
}

// ---------------------------------------------------------------------------
// Causal flash attention. qkv bf16 [B*T][2304] (q|k|v each H*64).
// Block = 256 thr = 4 waves; QBLK=64 (16 q-rows/wave), KBLK=64.
// grid = 48 (b,h) * 32 q-tiles.
// ---------------------------------------------------------------------------
__global__ __launch_bounds__(256) void attn_kernel(const u16* __restrict__ qkv,
                                                   u16* __restrict__ ctx) {
    int bid = blockIdx.x;
    int qt = bid & 31;           // q-tile
    int bh = bid >> 5;
    int b = bh / 12, h = bh % 12;
    int q0 = qt * 64;
    int tid = threadIdx.x, wid = tid >> 6, lane = tid & 63;
    int l15 = lane & 15, lhi = lane >> 4;

    __shared__ __align__(16) u16 lK[64 * 72];
    __shared__ __align__(16) u16 lV[64 * 72];      // transposed: [d][key]
    __shared__ __align__(16) u16 lP[4][16 * 72];   // per-wave P tile

    const size_t rowb = (size_t)b * 2048;

    // Q fragments (A layout: row = lane&15, k = 8*(lane>>4)+j)
    short8 aq[2];
    int qrow = q0 + wid * 16 + l15;
#pragma unroll
    for (int ks = 0; ks < 2; ks++)
        aq[ks] = *(const short8*)(qkv + (rowb + qrow) * 2304 + h * 64 + ks * 32 + lhi * 8);

    f32x4 o[4];
#pragma unroll
    for (int i = 0; i < 4; i++) o[i] = (f32x4)0.0f;
    float mrun[4], lrun[4];
#pragma unroll
    for (int r = 0; r < 4; r++) { mrun[r] = -1e30f; lrun[r] = 0.0f; }

    int nt = qt + 1;
    for (int t = 0; t < nt; t++) {
        int k0 = t * 64;
        // stage K [key][d]
#pragma unroll
        for (int i = tid; i < 512; i += 256) {
            int row = i >> 3, c = i & 7;
            *(float4*)(&lK[row * 72 + c * 8]) =
                *(const float4*)(qkv + (rowb + k0 + row) * 2304 + 768 + h * 64 + c * 8);
        }
        // stage V transposed -> lV[d][key]
#pragma unroll
        for (int i = tid; i < 512; i += 256) {
            int key = i >> 3, c = i & 7;
            float4 v4 = *(const float4*)(qkv + (rowb + k0 + key) * 2304 + 1536 + h * 64 + c * 8);
            const u16* vp = (const u16*)&v4;
#pragma unroll
            for (int j = 0; j < 8; j++) lV[(c * 8 + j) * 72 + key] = vp[j];
        }
        __syncthreads();

        // S = Q K^T  (4 col-tiles of 16 keys)
        f32x4 s[4];
#pragma unroll
        for (int ct = 0; ct < 4; ct++) {
            f32x4 a = (f32x4)0.0f;
#pragma unroll
            for (int ks = 0; ks < 2; ks++) {
                short8 bk = *(const short8*)(&lK[(ct * 16 + l15) * 72 + ks * 32 + lhi * 8]);
                a = __builtin_amdgcn_mfma_f32_16x16x32_bf16(aq[ks], bk, a, 0, 0, 0);
            }
            s[ct] = a;
        }
        // online softmax (D layout: row=(lane>>4)*4+r, col=lane&15)
#pragma unroll
        for (int r = 0; r < 4; r++) {
            int qr = q0 + wid * 16 + lhi * 4 + r;
            float tm = -1e30f;
#pragma unroll
            for (int ct = 0; ct < 4; ct++) {
                float sv = s[ct][r] * 0.125f;
                int kc = k0 + ct * 16 + l15;
                if (kc > qr) sv = -1e30f;
                s[ct][r] = sv;
                tm = fmaxf(tm, sv);
            }
#pragma unroll
            for (int off = 1; off < 16; off <<= 1) tm = fmaxf(tm, __shfl_xor(tm, off));
            float mnew = fmaxf(mrun[r], tm);
            float corr = __expf(mrun[r] - mnew);
            float rs = 0.0f;
#pragma unroll
            for (int ct = 0; ct < 4; ct++) {
                float p = __expf(s[ct][r] - mnew);
                s[ct][r] = p;
                rs += p;
            }
#pragma unroll
            for (int off = 1; off < 16; off <<= 1) rs += __shfl_xor(rs, off);
            lrun[r] = lrun[r] * corr + rs;
            mrun[r] = mnew;
#pragma unroll
            for (int dt = 0; dt < 4; dt++) o[dt][r] *= corr;
#pragma unroll
            for (int ct = 0; ct < 4; ct++)
                lP[wid][(lhi * 4 + r) * 72 + ct * 16 + l15] = f2bf(s[ct][r]);
        }
        __syncthreads();
        // PV: o += P[16x64] @ V[64x16]
#pragma unroll
        for (int ks = 0; ks < 2; ks++) {
            short8 ap = *(const short8*)(&lP[wid][l15 * 72 + ks * 32 + lhi * 8]);
#pragma unroll
            for (int dt = 0; dt < 4; dt++) {
                short8 bv = *(const short8*)(&lV[(dt * 16 + l15) * 72 + ks * 32 + lhi * 8]);
                o[dt] = __builtin_amdgcn_mfma_f32_16x16x32_bf16(ap, bv, o[dt], 0, 0, 0);
            }
        }
        __syncthreads();
    }
    // write ctx
#pragma unroll
    for (int r = 0; r < 4; r++) {
        float inv = 1.0f / lrun[r];
        int row = q0 + wid * 16 + lhi * 4 + r;
#pragma unroll
        for (int dt = 0; dt < 4; dt++)
            ctx[(rowb + row) * 768 + h * 64 + dt * 16 + l15] = f2bf(o[dt][r] * inv);
    }
}

// ---------------------------------------------------------------------------
extern "C" void kernel_launch(void* const* d_in, const int* in_sizes, int n_in,
                              void* d_out, int out_size, void* d_ws, size_t ws_size,
                              hipStream_t stream) {
    const float* x      = (const float*)d_in[0];
    // d_in[1] = mask (causal, implicit)
    const float* ln1_s  = (const float*)d_in[2];
    const float* ln1_b  = (const float*)d_in[3];
    const float* w_attn = (const float*)d_in[4];
    const float* b_attn = (const float*)d_in[5];
    const float* w_o    = (const float*)d_in[6];
    const float* b_o    = (const float*)d_in[7];
    const float* ln2_s  = (const float*)d_in[8];
    const float* ln2_b  = (const float*)d_in[9];
    const float* w_fc   = (const float*)d_in[10];
    const float* b_fc   = (const float*)d_in[11];
    const float* w_proj = (const float*)d_in[12];
    const float* b_proj = (const float*)d_in[13];

    char* ws = (char*)d_ws;
    u16* wT_attn = (u16*)(ws + 0);           // [2304][768]  3,538,944 B
    u16* wT_o    = (u16*)(ws + 3538944);     // [768][768]   1,179,648 B
    u16* wT_fc   = (u16*)(ws + 4718592);     // [3072][768]  4,718,592 B
    u16* wT_proj = (u16*)(ws + 9437184);     // [768][3072]  4,718,592 B
    u16* bufA    = (u16*)(ws + 14155776);    // bf16 [8192][768]  (h / ctx / h2)
    u16* bufB    = (u16*)(ws + 26738688);    // bf16 qkv [8192][2304] / act [8192][3072]
    float* x1    = (float*)(ws + 77070336);  // fp32 [8192][768]

    dim3 tb(32, 8);
    transpose_bf16_kernel<<<dim3(2304 / 32, 768 / 32), tb, 0, stream>>>(w_attn, wT_attn, 768, 2304);
    transpose_bf16_kernel<<<dim3(768 / 32, 768 / 32), tb, 0, stream>>>(w_o, wT_o, 768, 768);
    transpose_bf16_kernel<<<dim3(3072 / 32, 768 / 32), tb, 0, stream>>>(w_fc, wT_fc, 768, 3072);
    transpose_bf16_kernel<<<dim3(768 / 32, 3072 / 32), tb, 0, stream>>>(w_proj, wT_proj, 3072, 768);

    // LN1: x -> h (bufA)
    ln_kernel<<<8192, 256, 0, stream>>>(x, ln1_s, ln1_b, bufA);
    // QKV: h @ w_attn + b_attn -> qkv bf16 (bufB)
    gemm_kernel<0, 0, 1><<<dim3(64, 18), 256, 0, stream>>>(bufA, wT_attn, b_attn, nullptr, bufB, 8192, 2304, 768);
    // attention -> ctx (bufA)
    attn_kernel<<<48 * 32, 256, 0, stream>>>(bufB, bufA);
    // ctx @ w_o + b_o + x -> x1 fp32
    gemm_kernel<0, 1, 0><<<dim3(64, 6), 256, 0, stream>>>(bufA, wT_o, b_o, x, x1, 8192, 768, 768);
    // LN2: x1 -> h2 (bufA)
    ln_kernel<<<8192, 256, 0, stream>>>(x1, ln2_s, ln2_b, bufA);
    // FC: h2 @ w_fc + b_fc, GELU -> act bf16 (bufB)
    gemm_kernel<1, 0, 1><<<dim3(64, 24), 256, 0, stream>>>(bufA, wT_fc, b_fc, nullptr, bufB, 8192, 3072, 768);
    // proj: act @ w_proj + b_proj + x1 -> d_out fp32
    gemm_kernel<0, 1, 0><<<dim3(64, 6), 256, 0, stream>>>(bufB, wT_proj, b_proj, x1, (float*)d_out, 8192, 768, 3072);
}

// Round 2
// 348.468 us; speedup vs baseline: 1.8012x; 1.8012x over previous
//
#include <hip/hip_runtime.h>

// ---------------------------------------------------------------------------
// GPT-2 block: LN1 -> QKV GEMM (scatter q/k/vT) -> causal flash attn ->
//              proj+res -> LN2 -> FC+GELU -> proj+res
// B=4 T=2048 C=768 H=12 HD=64. MFMA bf16 16x16x32, fp32 accum.
// GEMMs: m97 structure (global_load_lds 16B, linear LDS + XOR swizzle).
// ---------------------------------------------------------------------------

typedef unsigned short u16;
typedef __attribute__((ext_vector_type(8))) short short8;  // 8 bf16 = 4 VGPR
typedef __attribute__((ext_vector_type(4))) float f32x4;   // MFMA C/D

__device__ __forceinline__ u16 f2bf(float f) {
    union { float f; unsigned u; } v; v.f = f;
    unsigned u = v.u;
    unsigned r = (u + 0x7FFFu + ((u >> 16) & 1u)) >> 16;
    return (u16)r;
}

// async global->LDS, 16B per lane. dest must be wave-uniform base + lane*16.
__device__ __forceinline__ void gld16(const u16* g, u16* l) {
    __builtin_amdgcn_global_load_lds(
        (const __attribute__((address_space(1))) void*)g,
        (__attribute__((address_space(3))) void*)l, 16, 0, 0);
}

// ---------------------------------------------------------------------------
// Weight transpose+convert: fp32 W[K][N] -> bf16 Wt[N][K]
// ---------------------------------------------------------------------------
__global__ void transpose_bf16_kernel(const float* __restrict__ w,
                                      u16* __restrict__ wt, int K, int N) {
    __shared__ float t[32][33];
    int n0 = blockIdx.x * 32, k0 = blockIdx.y * 32;
    int tx = threadIdx.x, ty = threadIdx.y;  // 32 x 8
#pragma unroll
    for (int i = 0; i < 4; i++)
        t[ty + 8 * i][tx] = w[(size_t)(k0 + ty + 8 * i) * N + n0 + tx];
    __syncthreads();
#pragma unroll
    for (int i = 0; i < 4; i++)
        wt[(size_t)(n0 + ty + 8 * i) * K + k0 + tx] = f2bf(t[tx][ty + 8 * i]);
}

// ---------------------------------------------------------------------------
// LayerNorm: fp32 [rows][768] -> bf16 [rows][768]
// ---------------------------------------------------------------------------
__global__ void ln_kernel(const float* __restrict__ x, const float* __restrict__ s,
                          const float* __restrict__ b, u16* __restrict__ out) {
    int row = blockIdx.x;
    int tid = threadIdx.x;
    const float* xr = x + (size_t)row * 768;
    float v0 = xr[tid], v1 = xr[tid + 256], v2 = xr[tid + 512];
    float sum = v0 + v1 + v2;
    float sq = v0 * v0 + v1 * v1 + v2 * v2;
#pragma unroll
    for (int off = 32; off; off >>= 1) {
        sum += __shfl_down(sum, off);
        sq += __shfl_down(sq, off);
    }
    __shared__ float red[8];
    int wid = tid >> 6, lane = tid & 63;
    if (lane == 0) { red[wid] = sum; red[4 + wid] = sq; }
    __syncthreads();
    if (tid == 0) {
        float s4 = red[0] + red[1] + red[2] + red[3];
        float q4 = red[4] + red[5] + red[6] + red[7];
        red[0] = s4 * (1.0f / 768.0f);
        red[1] = q4 * (1.0f / 768.0f);
    }
    __syncthreads();
    float mean = red[0];
    float var = red[1] - mean * mean;
    float rstd = rsqrtf(var + 1e-5f);
    u16* orow = out + (size_t)row * 768;
    orow[tid]       = f2bf((v0 - mean) * rstd * s[tid]       + b[tid]);
    orow[tid + 256] = f2bf((v1 - mean) * rstd * s[tid + 256] + b[tid + 256]);
    orow[tid + 512] = f2bf((v2 - mean) * rstd * s[tid + 512] + b[tid + 512]);
}

// ---------------------------------------------------------------------------
// GEMM: out = act(A[M,K]bf16 @ Wt[N,K]^T bf16 + bias [+ res])
// OUTMODE: 0 = fp32 out, 1 = bf16 out, 2 = QKV scatter (q/k [b,h,t,d]; v [b,h,d,t])
// BM=BN=128 BK=64, 256 thr = 4 waves 2x2, 4x4 frags/wave.
// Staging: global_load_lds 16B, linear LDS [row][64] with c8 ^= row&7 swizzle
// on BOTH source address and frag read (rule #21).
// ---------------------------------------------------------------------------
template <int GELU, int RES, int OUTMODE>
__global__ __launch_bounds__(256) void gemm_kernel(
    const u16* __restrict__ A, const u16* __restrict__ Wt,
    const float* __restrict__ bias, const float* __restrict__ res,
    void* __restrict__ out, int M, int N, int K,
    u16* __restrict__ qbuf, u16* __restrict__ kbuf, u16* __restrict__ vbuf) {
    __shared__ __align__(16) u16 lA[128 * 64];
    __shared__ __align__(16) u16 lB[128 * 64];
    int m0 = blockIdx.x * 128, n0 = blockIdx.y * 128;
    int tid = threadIdx.x;
    int wid = tid >> 6, lane = tid & 63;
    int wr = wid >> 1, wc = wid & 1;
    int l15 = lane & 15, lhi = lane >> 4;

    // staging source pointers (XOR-swizzled column)
    const u16* aptr[4];
    const u16* bptr[4];
#pragma unroll
    for (int s = 0; s < 4; s++) {
        int u = s * 256 + tid;
        int row = u >> 3;
        int c8 = (u & 7) ^ (row & 7);
        aptr[s] = A + (size_t)(m0 + row) * K + c8 * 8;
        bptr[s] = Wt + (size_t)(n0 + row) * K + c8 * 8;
    }

    f32x4 acc[4][4];
#pragma unroll
    for (int i = 0; i < 4; i++)
#pragma unroll
        for (int j = 0; j < 4; j++) acc[i][j] = (f32x4)0.0f;

    for (int k0 = 0; k0 < K; k0 += 64) {
#pragma unroll
        for (int s = 0; s < 4; s++) gld16(aptr[s] + k0, &lA[(s * 256 + tid) * 8]);
#pragma unroll
        for (int s = 0; s < 4; s++) gld16(bptr[s] + k0, &lB[(s * 256 + tid) * 8]);
        __syncthreads();
        short8 af[2][4], bfr[2][4];
#pragma unroll
        for (int ks = 0; ks < 2; ks++)
#pragma unroll
            for (int f = 0; f < 4; f++) {
                int ra = wr * 64 + f * 16 + l15;
                af[ks][f] = *(const short8*)&lA[ra * 64 + (((ks * 4 + lhi) ^ (ra & 7)) << 3)];
                int rb = wc * 64 + f * 16 + l15;
                bfr[ks][f] = *(const short8*)&lB[rb * 64 + (((ks * 4 + lhi) ^ (rb & 7)) << 3)];
            }
#pragma unroll
        for (int ks = 0; ks < 2; ks++)
#pragma unroll
            for (int fm = 0; fm < 4; fm++)
#pragma unroll
                for (int fn = 0; fn < 4; fn++)
                    acc[fm][fn] = __builtin_amdgcn_mfma_f32_16x16x32_bf16(
                        af[ks][fm], bfr[ks][fn], acc[fm][fn], 0, 0, 0);
        __syncthreads();
    }
    // epilogue: D layout row=(lane>>4)*4+r, col=lane&15
    if (OUTMODE == 2) {
        int region = n0 / 768;  // block-uniform: 768,1536 are multiples of 128
#pragma unroll
        for (int fm = 0; fm < 4; fm++)
#pragma unroll
            for (int fn = 0; fn < 4; fn++) {
                int col = n0 + wc * 64 + fn * 16 + l15;
                float bv = bias[col];
                int c = col - region * 768;
                int h = c >> 6, d = c & 63;
#pragma unroll
                for (int r = 0; r < 4; r++) {
                    int row = m0 + wr * 64 + fm * 16 + lhi * 4 + r;
                    int bb = row >> 11, t = row & 2047;
                    u16 val = f2bf(acc[fm][fn][r] + bv);
                    size_t bh = (size_t)bb * 12 + h;
                    if (region == 0)      qbuf[(bh * 2048 + t) * 64 + d] = val;
                    else if (region == 1) kbuf[(bh * 2048 + t) * 64 + d] = val;
                    else                  vbuf[(bh * 64 + d) * 2048 + t] = val;
                }
            }
    } else {
#pragma unroll
        for (int fm = 0; fm < 4; fm++)
#pragma unroll
            for (int fn = 0; fn < 4; fn++) {
                int col = n0 + wc * 64 + fn * 16 + l15;
                float bv = bias[col];
#pragma unroll
                for (int r = 0; r < 4; r++) {
                    int row = m0 + wr * 64 + fm * 16 + lhi * 4 + r;
                    float v = acc[fm][fn][r] + bv;
                    if (RES) v += res[(size_t)row * N + col];
                    if (GELU) {
                        float z = 0.7978845608028654f * (v + 0.044715f * v * v * v);
                        v = 0.5f * v * (1.0f + tanhf(z));
                    }
                    if (OUTMODE == 1)
                        ((u16*)out)[(size_t)row * N + col] = f2bf(v);
                    else
                        ((float*)out)[(size_t)row * N + col] = v;
                }
            }
    }
}

// ---------------------------------------------------------------------------
// Causal flash attention. q/k: bf16 [bh][t][64]; vT: bf16 [bh][64][t].
// QBLK=128 (4 waves x 32 rows), KBLK=64. Heavy q-tiles launch first.
// K and V^T staged via global_load_lds + XOR swizzle; P per-wave in LDS.
// ---------------------------------------------------------------------------
__global__ __launch_bounds__(256) void attn_kernel(const u16* __restrict__ qbuf,
                                                   const u16* __restrict__ kbuf,
                                                   const u16* __restrict__ vbuf,
                                                   u16* __restrict__ ctx) {
    int bid = blockIdx.x;
    int qt = 15 - (bid / 48);        // heavy tiles first
    int bh = bid % 48;
    int b = bh / 12, h = bh % 12;
    int q0 = qt * 128;
    int tid = threadIdx.x, wid = tid >> 6, lane = tid & 63;
    int l15 = lane & 15, lhi = lane >> 4;

    __shared__ __align__(16) u16 lK[64 * 64];   // [key][d] swizzled
    __shared__ __align__(16) u16 lV[64 * 64];   // [d][key] swizzled
    __shared__ __align__(16) u16 lP[4][32 * 72];

    const size_t bhT = (size_t)bh * 2048;

    // staging source pointers
    const u16* kptr[2];
    const u16* vptr[2];
#pragma unroll
    for (int s = 0; s < 2; s++) {
        int u = s * 256 + tid;
        int row = u >> 3;
        int c8 = (u & 7) ^ (row & 7);
        kptr[s] = kbuf + (bhT + row) * 64 + c8 * 8;              // + k0*64
        vptr[s] = vbuf + (bhT * 64 + (size_t)row * 2048) + c8 * 8;  // + k0
    }

    // Q fragments: a[j] = Q[lane&15][8*(lane>>4)+j]
    short8 aq[2][2];
#pragma unroll
    for (int rf = 0; rf < 2; rf++) {
        int qrow = q0 + wid * 32 + rf * 16 + l15;
#pragma unroll
        for (int ks = 0; ks < 2; ks++)
            aq[rf][ks] = *(const short8*)(qbuf + (bhT + qrow) * 64 + ks * 32 + lhi * 8);
    }

    f32x4 o[2][4];
#pragma unroll
    for (int rf = 0; rf < 2; rf++)
#pragma unroll
        for (int dt = 0; dt < 4; dt++) o[rf][dt] = (f32x4)0.0f;
    float mrun[2][4], lrun[2][4];
#pragma unroll
    for (int rf = 0; rf < 2; rf++)
#pragma unroll
        for (int r = 0; r < 4; r++) { mrun[rf][r] = -1e30f; lrun[rf][r] = 0.0f; }

    int nt = 2 * qt + 2;
    for (int t = 0; t < nt; t++) {
        int k0 = t * 64;
#pragma unroll
        for (int s = 0; s < 2; s++) gld16(kptr[s] + (size_t)k0 * 64, &lK[(s * 256 + tid) * 8]);
#pragma unroll
        for (int s = 0; s < 2; s++) gld16(vptr[s] + k0, &lV[(s * 256 + tid) * 8]);
        __syncthreads();

        // S = Q K^T
        f32x4 sc[2][4];
#pragma unroll
        for (int ct = 0; ct < 4; ct++) {
            int rk = ct * 16 + l15;
#pragma unroll
            for (int rf = 0; rf < 2; rf++) sc[rf][ct] = (f32x4)0.0f;
#pragma unroll
            for (int ks = 0; ks < 2; ks++) {
                short8 bk = *(const short8*)&lK[rk * 64 + (((ks * 4 + lhi) ^ (rk & 7)) << 3)];
#pragma unroll
                for (int rf = 0; rf < 2; rf++)
                    sc[rf][ct] = __builtin_amdgcn_mfma_f32_16x16x32_bf16(aq[rf][ks], bk, sc[rf][ct], 0, 0, 0);
            }
        }
        // online softmax; D layout row=(lane>>4)*4+r, col=lane&15
        bool masked = (t >= 2 * qt);
#pragma unroll
        for (int rf = 0; rf < 2; rf++)
#pragma unroll
            for (int r = 0; r < 4; r++) {
                int qr = q0 + wid * 32 + rf * 16 + lhi * 4 + r;
                float tm = -1e30f;
#pragma unroll
                for (int ct = 0; ct < 4; ct++) {
                    float sv = sc[rf][ct][r] * 0.125f;
                    if (masked) { if (k0 + ct * 16 + l15 > qr) sv = -1e30f; }
                    sc[rf][ct][r] = sv;
                    tm = fmaxf(tm, sv);
                }
#pragma unroll
                for (int off = 1; off < 16; off <<= 1) tm = fmaxf(tm, __shfl_xor(tm, off));
                float mnew = fmaxf(mrun[rf][r], tm);
                float corr = __expf(mrun[rf][r] - mnew);
                float rs = 0.0f;
#pragma unroll
                for (int ct = 0; ct < 4; ct++) {
                    float p = __expf(sc[rf][ct][r] - mnew);
                    sc[rf][ct][r] = p;
                    rs += p;
                }
#pragma unroll
                for (int off = 1; off < 16; off <<= 1) rs += __shfl_xor(rs, off);
                lrun[rf][r] = lrun[rf][r] * corr + rs;
                mrun[rf][r] = mnew;
#pragma unroll
                for (int dt = 0; dt < 4; dt++) o[rf][dt][r] *= corr;
#pragma unroll
                for (int ct = 0; ct < 4; ct++)
                    lP[wid][(rf * 16 + lhi * 4 + r) * 72 + ct * 16 + l15] = f2bf(sc[rf][ct][r]);
            }
        // PV: o[rf] += P[32x64] @ V[64x64] ; lP is wave-local (no barrier needed)
#pragma unroll
        for (int ks = 0; ks < 2; ks++) {
            short8 bv[4];
#pragma unroll
            for (int dt = 0; dt < 4; dt++) {
                int rd = dt * 16 + l15;
                bv[dt] = *(const short8*)&lV[rd * 64 + (((ks * 4 + lhi) ^ (rd & 7)) << 3)];
            }
#pragma unroll
            for (int rf = 0; rf < 2; rf++) {
                short8 ap = *(const short8*)&lP[wid][(rf * 16 + l15) * 72 + ks * 32 + lhi * 8];
#pragma unroll
                for (int dt = 0; dt < 4; dt++)
                    o[rf][dt] = __builtin_amdgcn_mfma_f32_16x16x32_bf16(ap, bv[dt], o[rf][dt], 0, 0, 0);
            }
        }
        __syncthreads();
    }
    // write ctx bf16 [b*2048+t][768]
    const size_t rowb = (size_t)b * 2048;
#pragma unroll
    for (int rf = 0; rf < 2; rf++)
#pragma unroll
        for (int r = 0; r < 4; r++) {
            float inv = 1.0f / lrun[rf][r];
            int row = q0 + wid * 32 + rf * 16 + lhi * 4 + r;
#pragma unroll
            for (int dt = 0; dt < 4; dt++)
                ctx[(rowb + row) * 768 + h * 64 + dt * 16 + l15] = f2bf(o[rf][dt][r] * inv);
        }
}

// ---------------------------------------------------------------------------
extern "C" void kernel_launch(void* const* d_in, const int* in_sizes, int n_in,
                              void* d_out, int out_size, void* d_ws, size_t ws_size,
                              hipStream_t stream) {
    const float* x      = (const float*)d_in[0];
    const float* ln1_s  = (const float*)d_in[2];
    const float* ln1_b  = (const float*)d_in[3];
    const float* w_attn = (const float*)d_in[4];
    const float* b_attn = (const float*)d_in[5];
    const float* w_o    = (const float*)d_in[6];
    const float* b_o    = (const float*)d_in[7];
    const float* ln2_s  = (const float*)d_in[8];
    const float* ln2_b  = (const float*)d_in[9];
    const float* w_fc   = (const float*)d_in[10];
    const float* b_fc   = (const float*)d_in[11];
    const float* w_proj = (const float*)d_in[12];
    const float* b_proj = (const float*)d_in[13];

    char* ws = (char*)d_ws;
    u16* wT_attn = (u16*)(ws + 0);           // [2304][768]
    u16* wT_o    = (u16*)(ws + 3538944);     // [768][768]
    u16* wT_fc   = (u16*)(ws + 4718592);     // [3072][768]
    u16* wT_proj = (u16*)(ws + 9437184);     // [768][3072]
    u16* bufA    = (u16*)(ws + 14155776);    // bf16 [8192][768] (h / ctx / h2)
    // region R (50.3MB): q/k/v layouts during attn, then reused as act
    u16* qbuf    = (u16*)(ws + 26738688);    // [48][2048][64]
    u16* kbuf    = (u16*)(ws + 39321600);    // [48][2048][64]
    u16* vbuf    = (u16*)(ws + 51904512);    // [48][64][2048]
    u16* act     = (u16*)(ws + 26738688);    // bf16 [8192][3072] (after attn)
    float* x1    = (float*)(ws + 77070336);  // fp32 [8192][768]

    dim3 tb(32, 8);
    transpose_bf16_kernel<<<dim3(2304 / 32, 768 / 32), tb, 0, stream>>>(w_attn, wT_attn, 768, 2304);
    transpose_bf16_kernel<<<dim3(768 / 32, 768 / 32), tb, 0, stream>>>(w_o, wT_o, 768, 768);
    transpose_bf16_kernel<<<dim3(3072 / 32, 768 / 32), tb, 0, stream>>>(w_fc, wT_fc, 768, 3072);
    transpose_bf16_kernel<<<dim3(768 / 32, 3072 / 32), tb, 0, stream>>>(w_proj, wT_proj, 3072, 768);

    // LN1: x -> h (bufA)
    ln_kernel<<<8192, 256, 0, stream>>>(x, ln1_s, ln1_b, bufA);
    // QKV: h @ w_attn + b_attn -> q/k/vT scatter
    gemm_kernel<0, 0, 2><<<dim3(64, 18), 256, 0, stream>>>(bufA, wT_attn, b_attn, nullptr, nullptr,
                                                           8192, 2304, 768, qbuf, kbuf, vbuf);
    // attention -> ctx (bufA)
    attn_kernel<<<768, 256, 0, stream>>>(qbuf, kbuf, vbuf, bufA);
    // ctx @ w_o + b_o + x -> x1 fp32
    gemm_kernel<0, 1, 0><<<dim3(64, 6), 256, 0, stream>>>(bufA, wT_o, b_o, x, x1,
                                                          8192, 768, 768, nullptr, nullptr, nullptr);
    // LN2: x1 -> h2 (bufA)
    ln_kernel<<<8192, 256, 0, stream>>>(x1, ln2_s, ln2_b, bufA);
    // FC: h2 @ w_fc + b_fc, GELU -> act bf16
    gemm_kernel<1, 0, 1><<<dim3(64, 24), 256, 0, stream>>>(bufA, wT_fc, b_fc, nullptr, act,
                                                           8192, 3072, 768, nullptr, nullptr, nullptr);
    // proj: act @ w_proj + b_proj + x1 -> d_out fp32
    gemm_kernel<0, 1, 0><<<dim3(64, 6), 256, 0, stream>>>(act, wT_proj, b_proj, x1, (float*)d_out,
                                                          8192, 768, 3072, nullptr, nullptr, nullptr);
}

// Round 3
// 292.086 us; speedup vs baseline: 2.1489x; 1.1930x over previous
//
#include <hip/hip_runtime.h>

// ---------------------------------------------------------------------------
// GPT-2 block: LN1 -> QKV GEMM (scatter q/k/vT) -> causal flash attn ->
//              proj+res -> LN2 -> FC+GELU -> proj+res
// B=4 T=2048 C=768 H=12 HD=64. MFMA bf16, fp32 accum.
// Attn: swapped-QK^T 32x32x16 structure (S^T = K*Q^T), in-register softmax,
//       cvt_pk + lane-half-exchange P fragments (no P LDS round trip),
//       defer-rescale THR=8 nats.
// ---------------------------------------------------------------------------

typedef unsigned short u16;
typedef unsigned int u32;
typedef __attribute__((ext_vector_type(8))) short short8;   // 8 bf16 = 4 VGPR
typedef __attribute__((ext_vector_type(4))) float f32x4;
typedef __attribute__((ext_vector_type(16))) float f32x16;  // 32x32 MFMA C/D

__device__ __forceinline__ u16 f2bf(float f) {
    union { float f; unsigned u; } v; v.f = f;
    unsigned u = v.u;
    unsigned r = (u + 0x7FFFu + ((u >> 16) & 1u)) >> 16;
    return (u16)r;
}

__device__ __forceinline__ u32 cvtpk_bf16(float lo, float hi) {
    u32 r;
    asm("v_cvt_pk_bf16_f32 %0, %1, %2" : "=v"(r) : "v"(lo), "v"(hi));
    return r;
}

// async global->LDS, 16B per lane. dest must be wave-uniform base + lane*16.
__device__ __forceinline__ void gld16(const u16* g, u16* l) {
    __builtin_amdgcn_global_load_lds(
        (const __attribute__((address_space(1))) void*)g,
        (__attribute__((address_space(3))) void*)l, 16, 0, 0);
}

// ---------------------------------------------------------------------------
// Weight transpose+convert: fp32 W[K][N] -> bf16 Wt[N][K]
// ---------------------------------------------------------------------------
__global__ void transpose_bf16_kernel(const float* __restrict__ w,
                                      u16* __restrict__ wt, int K, int N) {
    __shared__ float t[32][33];
    int n0 = blockIdx.x * 32, k0 = blockIdx.y * 32;
    int tx = threadIdx.x, ty = threadIdx.y;  // 32 x 8
#pragma unroll
    for (int i = 0; i < 4; i++)
        t[ty + 8 * i][tx] = w[(size_t)(k0 + ty + 8 * i) * N + n0 + tx];
    __syncthreads();
#pragma unroll
    for (int i = 0; i < 4; i++)
        wt[(size_t)(n0 + ty + 8 * i) * K + k0 + tx] = f2bf(t[tx][ty + 8 * i]);
}

// ---------------------------------------------------------------------------
// LayerNorm: fp32 [rows][768] -> bf16 [rows][768]
// ---------------------------------------------------------------------------
__global__ void ln_kernel(const float* __restrict__ x, const float* __restrict__ s,
                          const float* __restrict__ b, u16* __restrict__ out) {
    int row = blockIdx.x;
    int tid = threadIdx.x;
    const float* xr = x + (size_t)row * 768;
    float v0 = xr[tid], v1 = xr[tid + 256], v2 = xr[tid + 512];
    float sum = v0 + v1 + v2;
    float sq = v0 * v0 + v1 * v1 + v2 * v2;
#pragma unroll
    for (int off = 32; off; off >>= 1) {
        sum += __shfl_down(sum, off);
        sq += __shfl_down(sq, off);
    }
    __shared__ float red[8];
    int wid = tid >> 6, lane = tid & 63;
    if (lane == 0) { red[wid] = sum; red[4 + wid] = sq; }
    __syncthreads();
    if (tid == 0) {
        float s4 = red[0] + red[1] + red[2] + red[3];
        float q4 = red[4] + red[5] + red[6] + red[7];
        red[0] = s4 * (1.0f / 768.0f);
        red[1] = q4 * (1.0f / 768.0f);
    }
    __syncthreads();
    float mean = red[0];
    float var = red[1] - mean * mean;
    float rstd = rsqrtf(var + 1e-5f);
    u16* orow = out + (size_t)row * 768;
    orow[tid]       = f2bf((v0 - mean) * rstd * s[tid]       + b[tid]);
    orow[tid + 256] = f2bf((v1 - mean) * rstd * s[tid + 256] + b[tid + 256]);
    orow[tid + 512] = f2bf((v2 - mean) * rstd * s[tid + 512] + b[tid + 512]);
}

// ---------------------------------------------------------------------------
// GEMM: out = act(A[M,K]bf16 @ Wt[N,K]^T bf16 + bias [+ res])
// OUTMODE: 0 = fp32 out, 1 = bf16 out, 2 = QKV scatter (q/k [b,h,t,d]; v [b,h,d,t])
// ---------------------------------------------------------------------------
template <int GELU, int RES, int OUTMODE>
__global__ __launch_bounds__(256) void gemm_kernel(
    const u16* __restrict__ A, const u16* __restrict__ Wt,
    const float* __restrict__ bias, const float* __restrict__ res,
    void* __restrict__ out, int M, int N, int K,
    u16* __restrict__ qbuf, u16* __restrict__ kbuf, u16* __restrict__ vbuf) {
    __shared__ __align__(16) u16 lA[128 * 64];
    __shared__ __align__(16) u16 lB[128 * 64];
    int m0 = blockIdx.x * 128, n0 = blockIdx.y * 128;
    int tid = threadIdx.x;
    int wid = tid >> 6, lane = tid & 63;
    int wr = wid >> 1, wc = wid & 1;
    int l15 = lane & 15, lhi = lane >> 4;

    const u16* aptr[4];
    const u16* bptr[4];
#pragma unroll
    for (int s = 0; s < 4; s++) {
        int u = s * 256 + tid;
        int row = u >> 3;
        int c8 = (u & 7) ^ (row & 7);
        aptr[s] = A + (size_t)(m0 + row) * K + c8 * 8;
        bptr[s] = Wt + (size_t)(n0 + row) * K + c8 * 8;
    }

    f32x4 acc[4][4];
#pragma unroll
    for (int i = 0; i < 4; i++)
#pragma unroll
        for (int j = 0; j < 4; j++) acc[i][j] = (f32x4)0.0f;

    for (int k0 = 0; k0 < K; k0 += 64) {
#pragma unroll
        for (int s = 0; s < 4; s++) gld16(aptr[s] + k0, &lA[(s * 256 + tid) * 8]);
#pragma unroll
        for (int s = 0; s < 4; s++) gld16(bptr[s] + k0, &lB[(s * 256 + tid) * 8]);
        __syncthreads();
        short8 af[2][4], bfr[2][4];
#pragma unroll
        for (int ks = 0; ks < 2; ks++)
#pragma unroll
            for (int f = 0; f < 4; f++) {
                int ra = wr * 64 + f * 16 + l15;
                af[ks][f] = *(const short8*)&lA[ra * 64 + (((ks * 4 + lhi) ^ (ra & 7)) << 3)];
                int rb = wc * 64 + f * 16 + l15;
                bfr[ks][f] = *(const short8*)&lB[rb * 64 + (((ks * 4 + lhi) ^ (rb & 7)) << 3)];
            }
#pragma unroll
        for (int ks = 0; ks < 2; ks++)
#pragma unroll
            for (int fm = 0; fm < 4; fm++)
#pragma unroll
                for (int fn = 0; fn < 4; fn++)
                    acc[fm][fn] = __builtin_amdgcn_mfma_f32_16x16x32_bf16(
                        af[ks][fm], bfr[ks][fn], acc[fm][fn], 0, 0, 0);
        __syncthreads();
    }
    if (OUTMODE == 2) {
        int region = n0 / 768;
#pragma unroll
        for (int fm = 0; fm < 4; fm++)
#pragma unroll
            for (int fn = 0; fn < 4; fn++) {
                int col = n0 + wc * 64 + fn * 16 + l15;
                float bv = bias[col];
                int c = col - region * 768;
                int h = c >> 6, d = c & 63;
#pragma unroll
                for (int r = 0; r < 4; r++) {
                    int row = m0 + wr * 64 + fm * 16 + lhi * 4 + r;
                    int bb = row >> 11, t = row & 2047;
                    u16 val = f2bf(acc[fm][fn][r] + bv);
                    size_t bh = (size_t)bb * 12 + h;
                    if (region == 0)      qbuf[(bh * 2048 + t) * 64 + d] = val;
                    else if (region == 1) kbuf[(bh * 2048 + t) * 64 + d] = val;
                    else                  vbuf[(bh * 64 + d) * 2048 + t] = val;
                }
            }
    } else {
#pragma unroll
        for (int fm = 0; fm < 4; fm++)
#pragma unroll
            for (int fn = 0; fn < 4; fn++) {
                int col = n0 + wc * 64 + fn * 16 + l15;
                float bv = bias[col];
#pragma unroll
                for (int r = 0; r < 4; r++) {
                    int row = m0 + wr * 64 + fm * 16 + lhi * 4 + r;
                    float v = acc[fm][fn][r] + bv;
                    if (RES) v += res[(size_t)row * N + col];
                    if (GELU) {
                        float z = 0.7978845608028654f * (v + 0.044715f * v * v * v);
                        v = 0.5f * v * (1.0f + tanhf(z));
                    }
                    if (OUTMODE == 1)
                        ((u16*)out)[(size_t)row * N + col] = f2bf(v);
                    else
                        ((float*)out)[(size_t)row * N + col] = v;
                }
            }
    }
}

// ---------------------------------------------------------------------------
// Causal flash attention, swapped-QK^T 32x32 structure.
// q/k: bf16 [bh][t][64]; vT: bf16 [bh][64][t]. ctx: bf16 [b*T][768].
// Block = 256 thr = 4 waves; each wave owns 32 q-rows (QBLK=128), KVBLK=64.
// S^T = mfma(K, Q): lane&31 = q, keys in D regs -> in-register softmax.
// ---------------------------------------------------------------------------
__global__ __launch_bounds__(256) void attn_kernel(const u16* __restrict__ qbuf,
                                                   const u16* __restrict__ kbuf,
                                                   const u16* __restrict__ vbuf,
                                                   u16* __restrict__ ctx) {
    int bid = blockIdx.x;
    int qt = 15 - (bid / 48);        // heavy tiles first
    int bh = bid % 48;
    int b = bh / 12, h = bh % 12;
    int q0 = qt * 128;
    int tid = threadIdx.x, wid = tid >> 6, lane = tid & 63;
    int l31 = lane & 31, hi = lane >> 5;

    __shared__ __align__(16) u16 lK[64 * 64];   // [key][d] swizzled
    __shared__ __align__(16) u16 lV[64 * 64];   // [d][key] swizzled

    const size_t bhT = (size_t)bh * 2048;

    // staging source pointers (inverse-swizzled global addresses)
    const u16* kp[2];
    const u16* vp[2];
#pragma unroll
    for (int s = 0; s < 2; s++) {
        int u = s * 256 + tid;
        int row = u >> 3;
        int c8 = (u & 7) ^ (row & 7);
        kp[s] = kbuf + (bhT + row) * 64 + c8 * 8;                    // + k0*64
        vp[s] = vbuf + ((size_t)bh * 64 + row) * 2048 + c8 * 8;      // + k0
    }

    // Q B-fragments: b[j] = Q[q=l31][d = ks*16 + 8*hi + j]
    int qrow = q0 + wid * 32 + l31;
    short8 bq[4];
#pragma unroll
    for (int ks = 0; ks < 4; ks++)
        bq[ks] = *(const short8*)(qbuf + (bhT + qrow) * 64 + ks * 16 + hi * 8);

    f32x16 oacc[2];
#pragma unroll
    for (int dt = 0; dt < 2; dt++) oacc[dt] = (f32x16)0.0f;
    float mb = -1e30f, lr = 0.0f;    // running max (log2 dom) & denom, per q=l31
    const float C2 = 0.125f * 1.44269504089f;
    const float THR = 11.55f;        // 8 nats in log2
    int myq = q0 + wid * 32 + l31;
    int qmax = q0 + wid * 32 + 31;

    int nt = 2 * qt + 2;
    for (int t = 0; t < nt; t++) {
        int k0 = t * 64;
#pragma unroll
        for (int s = 0; s < 2; s++) gld16(kp[s] + (size_t)k0 * 64, &lK[(s * 256 + tid) * 8]);
#pragma unroll
        for (int s = 0; s < 2; s++) gld16(vp[s] + k0, &lV[(s * 256 + tid) * 8]);
        __syncthreads();

        if (k0 <= qmax) {   // skip fully-masked tiles for this wave
            // S^T = K * Q^T : 2 key-tiles of 32, 4 k-steps of 16 (d)
            f32x16 sa[2];
#pragma unroll
            for (int kt = 0; kt < 2; kt++) sa[kt] = (f32x16)0.0f;
#pragma unroll
            for (int kt = 0; kt < 2; kt++) {
                int rk = kt * 32 + l31;
#pragma unroll
                for (int ks = 0; ks < 4; ks++) {
                    short8 ak = *(const short8*)&lK[rk * 64 + (((ks * 2 + hi) ^ (rk & 7)) << 3)];
                    sa[kt] = __builtin_amdgcn_mfma_f32_32x32x16_bf16(ak, bq[ks], sa[kt], 0, 0, 0);
                }
            }
            // causal mask (only boundary tiles)
            if (k0 + 63 > q0 + wid * 32) {
#pragma unroll
                for (int kt = 0; kt < 2; kt++)
#pragma unroll
                    for (int r = 0; r < 16; r++) {
                        int key = k0 + kt * 32 + (r & 3) + 8 * (r >> 2) + 4 * hi;
                        if (key > myq) sa[kt][r] = -1e30f;
                    }
            }
            // in-register max (raw), then to log2 domain
            float tmax = -1e30f;
#pragma unroll
            for (int kt = 0; kt < 2; kt++)
#pragma unroll
                for (int r = 0; r < 16; r++) tmax = fmaxf(tmax, sa[kt][r]);
            tmax = fmaxf(tmax, __shfl_xor(tmax, 32));
            float tmb = tmax * C2;
            // defer-rescale
            if (__any(tmb > mb + THR)) {
                float mbn = fmaxf(mb, tmb);
                float corr = __builtin_amdgcn_exp2f(mb - mbn);
#pragma unroll
                for (int r = 0; r < 16; r++) {
                    int qm = (r & 3) + 8 * (r >> 2) + 4 * hi;
                    float c = __shfl(corr, qm);
                    oacc[0][r] *= c;
                    oacc[1][r] *= c;
                }
                lr *= corr;
                mb = mbn;
            }
            // p = exp2(s*C2 - mb); accumulate row sum
            float rs = 0.0f;
#pragma unroll
            for (int kt = 0; kt < 2; kt++)
#pragma unroll
                for (int r = 0; r < 16; r++) {
                    float pv = __builtin_amdgcn_exp2f(fmaf(sa[kt][r], C2, -mb));
                    sa[kt][r] = pv;
                    rs += pv;
                }
            rs += __shfl_xor(rs, 32);
            lr += rs;
            // cvt_pk + half-exchange -> P A-fragments (keys lane-local)
            short8 pa[4];
#pragma unroll
            for (int kt = 0; kt < 2; kt++)
#pragma unroll
                for (int ks2 = 0; ks2 < 2; ks2++) {
                    int base = ks2 * 8;
                    u32 A0 = cvtpk_bf16(sa[kt][base + 0], sa[kt][base + 1]);
                    u32 B0 = cvtpk_bf16(sa[kt][base + 4], sa[kt][base + 5]);
                    u32 A1 = cvtpk_bf16(sa[kt][base + 2], sa[kt][base + 3]);
                    u32 B1 = cvtpk_bf16(sa[kt][base + 6], sa[kt][base + 7]);
                    u32 A0s = (u32)__shfl_xor((int)A0, 32);
                    u32 B0s = (u32)__shfl_xor((int)B0, 32);
                    u32 A1s = (u32)__shfl_xor((int)A1, 32);
                    u32 B1s = (u32)__shfl_xor((int)B1, 32);
                    union { u32 u[4]; short8 s; } w;
                    w.u[0] = hi ? B0s : A0;
                    w.u[1] = hi ? B1s : A1;
                    w.u[2] = hi ? B0 : A0s;
                    w.u[3] = hi ? B1 : A1s;
                    pa[kt * 2 + ks2] = w.s;
                }
            // PV: O[q][d] += P * V
#pragma unroll
            for (int kt = 0; kt < 2; kt++)
#pragma unroll
                for (int ks2 = 0; ks2 < 2; ks2++) {
                    short8 ap = pa[kt * 2 + ks2];
#pragma unroll
                    for (int dt = 0; dt < 2; dt++) {
                        int rd = dt * 32 + l31;
                        short8 bv = *(const short8*)&lV[rd * 64 + (((kt * 4 + ks2 * 2 + hi) ^ (rd & 7)) << 3)];
                        oacc[dt] = __builtin_amdgcn_mfma_f32_32x32x16_bf16(ap, bv, oacc[dt], 0, 0, 0);
                    }
                }
        }
        __syncthreads();
    }
    // normalize and store: O rows q=(r&3)+8*(r>>2)+4*hi, col d = dt*32+l31
    const size_t rowb = (size_t)b * 2048;
    float inv = 1.0f / lr;
#pragma unroll
    for (int r = 0; r < 16; r++) {
        int qm = (r & 3) + 8 * (r >> 2) + 4 * hi;
        float ir = __shfl(inv, qm);
        int row = q0 + wid * 32 + qm;
        u16* op = ctx + (rowb + row) * 768 + h * 64 + l31;
        op[0]  = f2bf(oacc[0][r] * ir);
        op[32] = f2bf(oacc[1][r] * ir);
    }
}

// ---------------------------------------------------------------------------
extern "C" void kernel_launch(void* const* d_in, const int* in_sizes, int n_in,
                              void* d_out, int out_size, void* d_ws, size_t ws_size,
                              hipStream_t stream) {
    const float* x      = (const float*)d_in[0];
    const float* ln1_s  = (const float*)d_in[2];
    const float* ln1_b  = (const float*)d_in[3];
    const float* w_attn = (const float*)d_in[4];
    const float* b_attn = (const float*)d_in[5];
    const float* w_o    = (const float*)d_in[6];
    const float* b_o    = (const float*)d_in[7];
    const float* ln2_s  = (const float*)d_in[8];
    const float* ln2_b  = (const float*)d_in[9];
    const float* w_fc   = (const float*)d_in[10];
    const float* b_fc   = (const float*)d_in[11];
    const float* w_proj = (const float*)d_in[12];
    const float* b_proj = (const float*)d_in[13];

    char* ws = (char*)d_ws;
    u16* wT_attn = (u16*)(ws + 0);           // [2304][768]
    u16* wT_o    = (u16*)(ws + 3538944);     // [768][768]
    u16* wT_fc   = (u16*)(ws + 4718592);     // [3072][768]
    u16* wT_proj = (u16*)(ws + 9437184);     // [768][3072]
    u16* bufA    = (u16*)(ws + 14155776);    // bf16 [8192][768] (h / ctx / h2)
    u16* qbuf    = (u16*)(ws + 26738688);    // [48][2048][64]
    u16* kbuf    = (u16*)(ws + 39321600);    // [48][2048][64]
    u16* vbuf    = (u16*)(ws + 51904512);    // [48][64][2048]
    u16* act     = (u16*)(ws + 26738688);    // bf16 [8192][3072] (after attn)
    float* x1    = (float*)(ws + 77070336);  // fp32 [8192][768]

    dim3 tb(32, 8);
    transpose_bf16_kernel<<<dim3(2304 / 32, 768 / 32), tb, 0, stream>>>(w_attn, wT_attn, 768, 2304);
    transpose_bf16_kernel<<<dim3(768 / 32, 768 / 32), tb, 0, stream>>>(w_o, wT_o, 768, 768);
    transpose_bf16_kernel<<<dim3(3072 / 32, 768 / 32), tb, 0, stream>>>(w_fc, wT_fc, 768, 3072);
    transpose_bf16_kernel<<<dim3(768 / 32, 3072 / 32), tb, 0, stream>>>(w_proj, wT_proj, 3072, 768);

    ln_kernel<<<8192, 256, 0, stream>>>(x, ln1_s, ln1_b, bufA);
    gemm_kernel<0, 0, 2><<<dim3(64, 18), 256, 0, stream>>>(bufA, wT_attn, b_attn, nullptr, nullptr,
                                                           8192, 2304, 768, qbuf, kbuf, vbuf);
    attn_kernel<<<768, 256, 0, stream>>>(qbuf, kbuf, vbuf, bufA);
    gemm_kernel<0, 1, 0><<<dim3(64, 6), 256, 0, stream>>>(bufA, wT_o, b_o, x, x1,
                                                          8192, 768, 768, nullptr, nullptr, nullptr);
    ln_kernel<<<8192, 256, 0, stream>>>(x1, ln2_s, ln2_b, bufA);
    gemm_kernel<1, 0, 1><<<dim3(64, 24), 256, 0, stream>>>(bufA, wT_fc, b_fc, nullptr, act,
                                                           8192, 3072, 768, nullptr, nullptr, nullptr);
    gemm_kernel<0, 1, 0><<<dim3(64, 6), 256, 0, stream>>>(act, wT_proj, b_proj, x1, (float*)d_out,
                                                          8192, 768, 3072, nullptr, nullptr, nullptr);
}

// Round 4
// 262.992 us; speedup vs baseline: 2.3866x; 1.1106x over previous
//
#include <hip/hip_runtime.h>

// ---------------------------------------------------------------------------
// GPT-2 block: LN1 -> QKV GEMM (scatter q/k/vT) -> causal flash attn ->
//              proj+res -> LN2 -> FC+GELU -> proj+res
// B=4 T=2048 C=768 H=12 HD=64. MFMA bf16, fp32 accum.
// GEMMs + attn: 2-phase double-buffered LDS staging (stage t+1 while
// computing t, one barrier/tile). GELU via sigmoid identity (no tanhf).
// ---------------------------------------------------------------------------

typedef unsigned short u16;
typedef unsigned int u32;
typedef __attribute__((ext_vector_type(8))) short short8;   // 8 bf16 = 4 VGPR
typedef __attribute__((ext_vector_type(4))) float f32x4;
typedef __attribute__((ext_vector_type(16))) float f32x16;  // 32x32 MFMA C/D

__device__ __forceinline__ u16 f2bf(float f) {
    union { float f; unsigned u; } v; v.f = f;
    unsigned u = v.u;
    unsigned r = (u + 0x7FFFu + ((u >> 16) & 1u)) >> 16;
    return (u16)r;
}

__device__ __forceinline__ u32 cvtpk_bf16(float lo, float hi) {
    u32 r;
    asm("v_cvt_pk_bf16_f32 %0, %1, %2" : "=v"(r) : "v"(lo), "v"(hi));
    return r;
}

// async global->LDS, 16B per lane. dest must be wave-uniform base + lane*16.
__device__ __forceinline__ void gld16(const u16* g, u16* l) {
    __builtin_amdgcn_global_load_lds(
        (const __attribute__((address_space(1))) void*)g,
        (__attribute__((address_space(3))) void*)l, 16, 0, 0);
}

// gelu_tanh(v) = 0.5 v (1 + tanh(0.79788456(v + 0.044715 v^3))) = v*sigmoid(2z)
__device__ __forceinline__ float gelu_fast(float v) {
    float t = v * v;
    float z2n = v * (-2.3022078f - 0.10294376f * t);   // -2z*log2(e)
    float e = __builtin_amdgcn_exp2f(z2n);             // e^{-2z}
    return v * __builtin_amdgcn_rcpf(1.0f + e);
}

// ---------------------------------------------------------------------------
// Weight transpose+convert: fp32 W[K][N] -> bf16 Wt[N][K]
// ---------------------------------------------------------------------------
__global__ void transpose_bf16_kernel(const float* __restrict__ w,
                                      u16* __restrict__ wt, int K, int N) {
    __shared__ float t[32][33];
    int n0 = blockIdx.x * 32, k0 = blockIdx.y * 32;
    int tx = threadIdx.x, ty = threadIdx.y;  // 32 x 8
#pragma unroll
    for (int i = 0; i < 4; i++)
        t[ty + 8 * i][tx] = w[(size_t)(k0 + ty + 8 * i) * N + n0 + tx];
    __syncthreads();
#pragma unroll
    for (int i = 0; i < 4; i++)
        wt[(size_t)(n0 + ty + 8 * i) * K + k0 + tx] = f2bf(t[tx][ty + 8 * i]);
}

// ---------------------------------------------------------------------------
// LayerNorm: fp32 [rows][768] -> bf16 [rows][768]
// ---------------------------------------------------------------------------
__global__ void ln_kernel(const float* __restrict__ x, const float* __restrict__ s,
                          const float* __restrict__ b, u16* __restrict__ out) {
    int row = blockIdx.x;
    int tid = threadIdx.x;
    const float* xr = x + (size_t)row * 768;
    float v0 = xr[tid], v1 = xr[tid + 256], v2 = xr[tid + 512];
    float sum = v0 + v1 + v2;
    float sq = v0 * v0 + v1 * v1 + v2 * v2;
#pragma unroll
    for (int off = 32; off; off >>= 1) {
        sum += __shfl_down(sum, off);
        sq += __shfl_down(sq, off);
    }
    __shared__ float red[8];
    int wid = tid >> 6, lane = tid & 63;
    if (lane == 0) { red[wid] = sum; red[4 + wid] = sq; }
    __syncthreads();
    if (tid == 0) {
        float s4 = red[0] + red[1] + red[2] + red[3];
        float q4 = red[4] + red[5] + red[6] + red[7];
        red[0] = s4 * (1.0f / 768.0f);
        red[1] = q4 * (1.0f / 768.0f);
    }
    __syncthreads();
    float mean = red[0];
    float var = red[1] - mean * mean;
    float rstd = rsqrtf(var + 1e-5f);
    u16* orow = out + (size_t)row * 768;
    orow[tid]       = f2bf((v0 - mean) * rstd * s[tid]       + b[tid]);
    orow[tid + 256] = f2bf((v1 - mean) * rstd * s[tid + 256] + b[tid + 256]);
    orow[tid + 512] = f2bf((v2 - mean) * rstd * s[tid + 512] + b[tid + 512]);
}

// ---------------------------------------------------------------------------
// GEMM: out = act(A[M,K]bf16 @ Wt[N,K]^T bf16 + bias [+ res])
// OUTMODE: 0 = fp32 out, 1 = bf16 out, 2 = QKV scatter (q/k [b,h,t,d]; v [b,h,d,t])
// 2-phase double-buffered staging: stage tile t+1 while computing tile t.
// ---------------------------------------------------------------------------
template <int GELU, int RES, int OUTMODE>
__global__ __launch_bounds__(256) void gemm_kernel(
    const u16* __restrict__ A, const u16* __restrict__ Wt,
    const float* __restrict__ bias, const float* __restrict__ res,
    void* __restrict__ out, int M, int N, int K,
    u16* __restrict__ qbuf, u16* __restrict__ kbuf, u16* __restrict__ vbuf) {
    __shared__ __align__(16) u16 lA[2][128 * 64];
    __shared__ __align__(16) u16 lB[2][128 * 64];
    int m0 = blockIdx.x * 128, n0 = blockIdx.y * 128;
    int tid = threadIdx.x;
    int wid = tid >> 6, lane = tid & 63;
    int wr = wid >> 1, wc = wid & 1;
    int l15 = lane & 15, lhi = lane >> 4;

    const u16* aptr[4];
    const u16* bptr[4];
#pragma unroll
    for (int s = 0; s < 4; s++) {
        int u = s * 256 + tid;
        int row = u >> 3;
        int c8 = (u & 7) ^ (row & 7);
        aptr[s] = A + (size_t)(m0 + row) * K + c8 * 8;
        bptr[s] = Wt + (size_t)(n0 + row) * K + c8 * 8;
    }

    f32x4 acc[4][4];
#pragma unroll
    for (int i = 0; i < 4; i++)
#pragma unroll
        for (int j = 0; j < 4; j++) acc[i][j] = (f32x4)0.0f;

    // prologue: stage tile 0 into buffer 0
#pragma unroll
    for (int s = 0; s < 4; s++) gld16(aptr[s], &lA[0][(s * 256 + tid) * 8]);
#pragma unroll
    for (int s = 0; s < 4; s++) gld16(bptr[s], &lB[0][(s * 256 + tid) * 8]);
    __syncthreads();

    int KT = K >> 6;
    int cur = 0;
    for (int t = 0; t < KT; t++) {
        if (t + 1 < KT) {
            int ko = (t + 1) << 6;
#pragma unroll
            for (int s = 0; s < 4; s++) gld16(aptr[s] + ko, &lA[cur ^ 1][(s * 256 + tid) * 8]);
#pragma unroll
            for (int s = 0; s < 4; s++) gld16(bptr[s] + ko, &lB[cur ^ 1][(s * 256 + tid) * 8]);
        }
        short8 af[2][4], bfr[2][4];
#pragma unroll
        for (int ks = 0; ks < 2; ks++)
#pragma unroll
            for (int f = 0; f < 4; f++) {
                int ra = wr * 64 + f * 16 + l15;
                af[ks][f] = *(const short8*)&lA[cur][ra * 64 + (((ks * 4 + lhi) ^ (ra & 7)) << 3)];
                int rb = wc * 64 + f * 16 + l15;
                bfr[ks][f] = *(const short8*)&lB[cur][rb * 64 + (((ks * 4 + lhi) ^ (rb & 7)) << 3)];
            }
#pragma unroll
        for (int ks = 0; ks < 2; ks++)
#pragma unroll
            for (int fm = 0; fm < 4; fm++)
#pragma unroll
                for (int fn = 0; fn < 4; fn++)
                    acc[fm][fn] = __builtin_amdgcn_mfma_f32_16x16x32_bf16(
                        af[ks][fm], bfr[ks][fn], acc[fm][fn], 0, 0, 0);
        __syncthreads();   // drains vmcnt(0): next tile ready; buf[cur] reusable
        cur ^= 1;
    }

    if (OUTMODE == 2) {
        int region = n0 / 768;
#pragma unroll
        for (int fm = 0; fm < 4; fm++)
#pragma unroll
            for (int fn = 0; fn < 4; fn++) {
                int col = n0 + wc * 64 + fn * 16 + l15;
                float bv = bias[col];
                int c = col - region * 768;
                int h = c >> 6, d = c & 63;
#pragma unroll
                for (int r = 0; r < 4; r++) {
                    int row = m0 + wr * 64 + fm * 16 + lhi * 4 + r;
                    int bb = row >> 11, t = row & 2047;
                    u16 val = f2bf(acc[fm][fn][r] + bv);
                    size_t bh = (size_t)bb * 12 + h;
                    if (region == 0)      qbuf[(bh * 2048 + t) * 64 + d] = val;
                    else if (region == 1) kbuf[(bh * 2048 + t) * 64 + d] = val;
                    else                  vbuf[(bh * 64 + d) * 2048 + t] = val;
                }
            }
    } else {
#pragma unroll
        for (int fm = 0; fm < 4; fm++)
#pragma unroll
            for (int fn = 0; fn < 4; fn++) {
                int col = n0 + wc * 64 + fn * 16 + l15;
                float bv = bias[col];
#pragma unroll
                for (int r = 0; r < 4; r++) {
                    int row = m0 + wr * 64 + fm * 16 + lhi * 4 + r;
                    float v = acc[fm][fn][r] + bv;
                    if (RES) v += res[(size_t)row * N + col];
                    if (GELU) v = gelu_fast(v);
                    if (OUTMODE == 1)
                        ((u16*)out)[(size_t)row * N + col] = f2bf(v);
                    else
                        ((float*)out)[(size_t)row * N + col] = v;
                }
            }
    }
}

// ---------------------------------------------------------------------------
// Causal flash attention, swapped-QK^T 32x32 structure, 2-phase K/V staging.
// q/k: bf16 [bh][t][64]; vT: bf16 [bh][64][t]. ctx: bf16 [b*T][768].
// ---------------------------------------------------------------------------
__global__ __launch_bounds__(256) void attn_kernel(const u16* __restrict__ qbuf,
                                                   const u16* __restrict__ kbuf,
                                                   const u16* __restrict__ vbuf,
                                                   u16* __restrict__ ctx) {
    int bid = blockIdx.x;
    int qt = 15 - (bid / 48);        // heavy tiles first
    int bh = bid % 48;
    int b = bh / 12, h = bh % 12;
    int q0 = qt * 128;
    int tid = threadIdx.x, wid = tid >> 6, lane = tid & 63;
    int l31 = lane & 31, hi = lane >> 5;

    __shared__ __align__(16) u16 lK[2][64 * 64];   // [key][d] swizzled
    __shared__ __align__(16) u16 lV[2][64 * 64];   // [d][key] swizzled

    const size_t bhT = (size_t)bh * 2048;

    const u16* kp[2];
    const u16* vp[2];
#pragma unroll
    for (int s = 0; s < 2; s++) {
        int u = s * 256 + tid;
        int row = u >> 3;
        int c8 = (u & 7) ^ (row & 7);
        kp[s] = kbuf + (bhT + row) * 64 + c8 * 8;                    // + k0*64
        vp[s] = vbuf + ((size_t)bh * 64 + row) * 2048 + c8 * 8;      // + k0
    }

    // Q B-fragments: b[j] = Q[q=l31][d = ks*16 + 8*hi + j]
    int qrow = q0 + wid * 32 + l31;
    short8 bq[4];
#pragma unroll
    for (int ks = 0; ks < 4; ks++)
        bq[ks] = *(const short8*)(qbuf + (bhT + qrow) * 64 + ks * 16 + hi * 8);

    f32x16 oacc[2];
#pragma unroll
    for (int dt = 0; dt < 2; dt++) oacc[dt] = (f32x16)0.0f;
    float mb = -1e30f, lr = 0.0f;
    const float C2 = 0.125f * 1.44269504089f;
    const float THR = 11.55f;
    int myq = q0 + wid * 32 + l31;
    int qmax = q0 + wid * 32 + 31;

    int nt = 2 * qt + 2;
    // prologue: stage tile 0
#pragma unroll
    for (int s = 0; s < 2; s++) gld16(kp[s], &lK[0][(s * 256 + tid) * 8]);
#pragma unroll
    for (int s = 0; s < 2; s++) gld16(vp[s], &lV[0][(s * 256 + tid) * 8]);
    __syncthreads();

    int cur = 0;
    for (int t = 0; t < nt; t++) {
        int k0 = t * 64;
        if (t + 1 < nt) {
            int kn = (t + 1) * 64;
#pragma unroll
            for (int s = 0; s < 2; s++) gld16(kp[s] + (size_t)kn * 64, &lK[cur ^ 1][(s * 256 + tid) * 8]);
#pragma unroll
            for (int s = 0; s < 2; s++) gld16(vp[s] + kn, &lV[cur ^ 1][(s * 256 + tid) * 8]);
        }
        if (k0 <= qmax) {
            f32x16 sa[2];
#pragma unroll
            for (int kt = 0; kt < 2; kt++) sa[kt] = (f32x16)0.0f;
#pragma unroll
            for (int kt = 0; kt < 2; kt++) {
                int rk = kt * 32 + l31;
#pragma unroll
                for (int ks = 0; ks < 4; ks++) {
                    short8 ak = *(const short8*)&lK[cur][rk * 64 + (((ks * 2 + hi) ^ (rk & 7)) << 3)];
                    sa[kt] = __builtin_amdgcn_mfma_f32_32x32x16_bf16(ak, bq[ks], sa[kt], 0, 0, 0);
                }
            }
            if (k0 + 63 > q0 + wid * 32) {
#pragma unroll
                for (int kt = 0; kt < 2; kt++)
#pragma unroll
                    for (int r = 0; r < 16; r++) {
                        int key = k0 + kt * 32 + (r & 3) + 8 * (r >> 2) + 4 * hi;
                        if (key > myq) sa[kt][r] = -1e30f;
                    }
            }
            float tmax = -1e30f;
#pragma unroll
            for (int kt = 0; kt < 2; kt++)
#pragma unroll
                for (int r = 0; r < 16; r++) tmax = fmaxf(tmax, sa[kt][r]);
            tmax = fmaxf(tmax, __shfl_xor(tmax, 32));
            float tmb = tmax * C2;
            if (__any(tmb > mb + THR)) {
                float mbn = fmaxf(mb, tmb);
                float corr = __builtin_amdgcn_exp2f(mb - mbn);
#pragma unroll
                for (int r = 0; r < 16; r++) {
                    int qm = (r & 3) + 8 * (r >> 2) + 4 * hi;
                    float c = __shfl(corr, qm);
                    oacc[0][r] *= c;
                    oacc[1][r] *= c;
                }
                lr *= corr;
                mb = mbn;
            }
            float rs = 0.0f;
#pragma unroll
            for (int kt = 0; kt < 2; kt++)
#pragma unroll
                for (int r = 0; r < 16; r++) {
                    float pv = __builtin_amdgcn_exp2f(fmaf(sa[kt][r], C2, -mb));
                    sa[kt][r] = pv;
                    rs += pv;
                }
            rs += __shfl_xor(rs, 32);
            lr += rs;
            short8 pa[4];
#pragma unroll
            for (int kt = 0; kt < 2; kt++)
#pragma unroll
                for (int ks2 = 0; ks2 < 2; ks2++) {
                    int base = ks2 * 8;
                    u32 A0 = cvtpk_bf16(sa[kt][base + 0], sa[kt][base + 1]);
                    u32 B0 = cvtpk_bf16(sa[kt][base + 4], sa[kt][base + 5]);
                    u32 A1 = cvtpk_bf16(sa[kt][base + 2], sa[kt][base + 3]);
                    u32 B1 = cvtpk_bf16(sa[kt][base + 6], sa[kt][base + 7]);
                    u32 A0s = (u32)__shfl_xor((int)A0, 32);
                    u32 B0s = (u32)__shfl_xor((int)B0, 32);
                    u32 A1s = (u32)__shfl_xor((int)A1, 32);
                    u32 B1s = (u32)__shfl_xor((int)B1, 32);
                    union { u32 u[4]; short8 s; } w;
                    w.u[0] = hi ? B0s : A0;
                    w.u[1] = hi ? B1s : A1;
                    w.u[2] = hi ? B0 : A0s;
                    w.u[3] = hi ? B1 : A1s;
                    pa[kt * 2 + ks2] = w.s;
                }
#pragma unroll
            for (int kt = 0; kt < 2; kt++)
#pragma unroll
                for (int ks2 = 0; ks2 < 2; ks2++) {
                    short8 ap = pa[kt * 2 + ks2];
#pragma unroll
                    for (int dt = 0; dt < 2; dt++) {
                        int rd = dt * 32 + l31;
                        short8 bv = *(const short8*)&lV[cur][rd * 64 + (((kt * 4 + ks2 * 2 + hi) ^ (rd & 7)) << 3)];
                        oacc[dt] = __builtin_amdgcn_mfma_f32_32x32x16_bf16(ap, bv, oacc[dt], 0, 0, 0);
                    }
                }
        }
        __syncthreads();
        cur ^= 1;
    }
    const size_t rowb = (size_t)b * 2048;
    float inv = 1.0f / lr;
#pragma unroll
    for (int r = 0; r < 16; r++) {
        int qm = (r & 3) + 8 * (r >> 2) + 4 * hi;
        float ir = __shfl(inv, qm);
        int row = q0 + wid * 32 + qm;
        u16* op = ctx + (rowb + row) * 768 + h * 64 + l31;
        op[0]  = f2bf(oacc[0][r] * ir);
        op[32] = f2bf(oacc[1][r] * ir);
    }
}

// ---------------------------------------------------------------------------
extern "C" void kernel_launch(void* const* d_in, const int* in_sizes, int n_in,
                              void* d_out, int out_size, void* d_ws, size_t ws_size,
                              hipStream_t stream) {
    const float* x      = (const float*)d_in[0];
    const float* ln1_s  = (const float*)d_in[2];
    const float* ln1_b  = (const float*)d_in[3];
    const float* w_attn = (const float*)d_in[4];
    const float* b_attn = (const float*)d_in[5];
    const float* w_o    = (const float*)d_in[6];
    const float* b_o    = (const float*)d_in[7];
    const float* ln2_s  = (const float*)d_in[8];
    const float* ln2_b  = (const float*)d_in[9];
    const float* w_fc   = (const float*)d_in[10];
    const float* b_fc   = (const float*)d_in[11];
    const float* w_proj = (const float*)d_in[12];
    const float* b_proj = (const float*)d_in[13];

    char* ws = (char*)d_ws;
    u16* wT_attn = (u16*)(ws + 0);           // [2304][768]
    u16* wT_o    = (u16*)(ws + 3538944);     // [768][768]
    u16* wT_fc   = (u16*)(ws + 4718592);     // [3072][768]
    u16* wT_proj = (u16*)(ws + 9437184);     // [768][3072]
    u16* bufA    = (u16*)(ws + 14155776);    // bf16 [8192][768] (h / ctx / h2)
    u16* qbuf    = (u16*)(ws + 26738688);    // [48][2048][64]
    u16* kbuf    = (u16*)(ws + 39321600);    // [48][2048][64]
    u16* vbuf    = (u16*)(ws + 51904512);    // [48][64][2048]
    u16* act     = (u16*)(ws + 26738688);    // bf16 [8192][3072] (after attn)
    float* x1    = (float*)(ws + 77070336);  // fp32 [8192][768]

    dim3 tb(32, 8);
    transpose_bf16_kernel<<<dim3(2304 / 32, 768 / 32), tb, 0, stream>>>(w_attn, wT_attn, 768, 2304);
    transpose_bf16_kernel<<<dim3(768 / 32, 768 / 32), tb, 0, stream>>>(w_o, wT_o, 768, 768);
    transpose_bf16_kernel<<<dim3(3072 / 32, 768 / 32), tb, 0, stream>>>(w_fc, wT_fc, 768, 3072);
    transpose_bf16_kernel<<<dim3(768 / 32, 3072 / 32), tb, 0, stream>>>(w_proj, wT_proj, 3072, 768);

    ln_kernel<<<8192, 256, 0, stream>>>(x, ln1_s, ln1_b, bufA);
    gemm_kernel<0, 0, 2><<<dim3(64, 18), 256, 0, stream>>>(bufA, wT_attn, b_attn, nullptr, nullptr,
                                                           8192, 2304, 768, qbuf, kbuf, vbuf);
    attn_kernel<<<768, 256, 0, stream>>>(qbuf, kbuf, vbuf, bufA);
    gemm_kernel<0, 1, 0><<<dim3(64, 6), 256, 0, stream>>>(bufA, wT_o, b_o, x, x1,
                                                          8192, 768, 768, nullptr, nullptr, nullptr);
    ln_kernel<<<8192, 256, 0, stream>>>(x1, ln2_s, ln2_b, bufA);
    gemm_kernel<1, 0, 1><<<dim3(64, 24), 256, 0, stream>>>(bufA, wT_fc, b_fc, nullptr, act,
                                                           8192, 3072, 768, nullptr, nullptr, nullptr);
    gemm_kernel<0, 1, 0><<<dim3(64, 6), 256, 0, stream>>>(act, wT_proj, b_proj, x1, (float*)d_out,
                                                          8192, 768, 3072, nullptr, nullptr, nullptr);
}